// Round 24
// baseline (204.196 us; speedup 1.0000x reference)
//
#include <hip/hip_runtime.h>

// B=4, S=2048, D=1024, H=16, HD=64. Inputs fp32, OUTPUT fp32.
// Intermediates bf16. ws: xb/Ao + Kb + Vtb + Wtp = 52.4MB.
// d_out double-duty: lower half = Q (bf16), upper half = Wtq (bf16) until proj.
typedef __bf16 bf16x8 __attribute__((ext_vector_type(8)));
typedef unsigned short ushort8 __attribute__((ext_vector_type(8)));
typedef float floatx4 __attribute__((ext_vector_type(4)));
typedef unsigned int uintx4 __attribute__((ext_vector_type(4)));

__device__ __forceinline__ unsigned short f2bf(float f) {
  unsigned int u = __builtin_bit_cast(unsigned int, f);
  u += 0x7fffu + ((u >> 16) & 1u);
  return (unsigned short)(u >> 16);
}
__device__ __forceinline__ unsigned int pkbf(float a, float b) {
  unsigned int r;
  asm("v_cvt_pk_bf16_f32 %0, %1, %2" : "=v"(r) : "v"(a), "v"(b));
  return r;
}
__device__ __forceinline__ floatx4 MFMA16(bf16x8 a, bf16x8 b, floatx4 c) {
  return __builtin_amdgcn_mfma_f32_16x16x32_bf16(a, b, c, 0, 0, 0);
}

#define GLOAD16(gsrc, ldst)                                                  \
  __builtin_amdgcn_global_load_lds(                                          \
      (const __attribute__((address_space(1))) void*)(gsrc),                 \
      (__attribute__((address_space(3))) void*)(ldst), 16, 0, 0)

__global__ __launch_bounds__(256) void fill_f32(
    float* __restrict__ out, float val, size_t n) {
  const size_t t = (size_t)blockIdx.x * 256 + threadIdx.x;
  for (size_t i = t; i < n; i += (size_t)gridDim.x * 256) out[i] = val;
}

// Fused prep: [0,4096) x fp32->bf16; [4096,4864) Wqkv transpose (48x16);
// [4864,5120) Wproj transpose (16x16). Wtp is a DEDICATED buffer (no alias).
__global__ __launch_bounds__(256) void prep_fused(
    const float* __restrict__ x, unsigned short* __restrict__ xb,
    const float* __restrict__ Wqkv, unsigned short* __restrict__ Wtq,
    const float* __restrict__ Wproj, unsigned short* __restrict__ Wtp) {
  const int blk = blockIdx.x;
  const int tid = threadIdx.x;
  if (blk < 4096) {  // cvt: 8 elems/thread
    const size_t t = (size_t)blk * 256 + tid;
    const float4 a = ((const float4*)x)[2 * t];
    const float4 b = ((const float4*)x)[2 * t + 1];
    uintx4 u;
    u[0] = pkbf(a.x, a.y); u[1] = pkbf(a.z, a.w);
    u[2] = pkbf(b.x, b.y); u[3] = pkbf(b.z, b.w);
    *(uintx4*)&xb[t * 8] = u;
    return;
  }
  const float* in;
  unsigned short* out;
  int C, bx, by;
  if (blk < 4864) {
    in = Wqkv; out = Wtq; C = 3072;
    const int b2 = blk - 4096;           // 48 x 16
    bx = b2 % 48; by = b2 / 48;
  } else {
    in = Wproj; out = Wtp; C = 1024;
    const int b2 = blk - 4864;           // 16 x 16
    bx = b2 % 16; by = b2 / 16;
  }
  __shared__ float T[64][65];
  const int r0 = by * 64, c0 = bx * 64;
#pragma unroll
  for (int e = 0; e < 4; ++e) {
    const int idx = e * 256 + tid;
    const int row = idx >> 4, cg = idx & 15;
    const float4 f = *(const float4*)&in[(size_t)(r0 + row) * C + c0 + cg * 4];
    T[row][cg * 4] = f.x; T[row][cg * 4 + 1] = f.y;
    T[row][cg * 4 + 2] = f.z; T[row][cg * 4 + 3] = f.w;
  }
  __syncthreads();
#pragma unroll
  for (int e = 0; e < 2; ++e) {
    const int idx = e * 256 + tid;
    const int cc = idx >> 3, rg = idx & 7;
    uintx4 u;
#pragma unroll
    for (int k = 0; k < 4; ++k)
      u[k] = pkbf(T[rg * 8 + 2 * k][cc], T[rg * 8 + 2 * k + 1][cc]);
    *(uintx4*)&out[(size_t)(c0 + cc) * 1024 + r0 + rg * 8] = u;
  }
}

// C[8192, NBX*128] = A[8192,1024](bf16) @ Bt[NBX*128,1024](bf16)^T + bias.
// BM=256, BN=128, BK=64, 8 waves. 3-deep LDS pipeline, counted vmcnt(6),
// PHASE-SPLIT body (T3+T4). XOR-swizzled LDS (both-sides).
template <int NBX, int EPI>
__global__ __launch_bounds__(512) void gemm8p(
    const unsigned short* __restrict__ A, const unsigned short* __restrict__ Bt,
    const float* __restrict__ bias, unsigned short* __restrict__ o0,
    unsigned short* __restrict__ o1, unsigned short* __restrict__ o2,
    float* __restrict__ of) {
  __shared__ __align__(16) unsigned short As[3][256 * 64];
  __shared__ __align__(16) unsigned short Bs[3][128 * 64];
  const int tid = threadIdx.x;
  const int lane = tid & 63;
  const int w = tid >> 6;
  const int g = lane >> 4, l15 = lane & 15;
  const int wr = w >> 1, wc = w & 1;
  constexpr int QX = 4 * NBX;
  const int orig = blockIdx.x;
  const int wgid = (orig & 7) * QX + (orig >> 3);
  const int m0 = (wgid / NBX) * 256, n0 = (wgid % NBX) * 128;

  floatx4 acc[4][4];
#pragma unroll
  for (int i = 0; i < 4; ++i)
#pragma unroll
    for (int j = 0; j < 4; ++j) acc[i][j] = {0.f, 0.f, 0.f, 0.f};

  const unsigned short* asrc[4];
  const unsigned short* bsrc[2];
  int adst[4], bdst[2];
#pragma unroll
  for (int p = 0; p < 4; ++p) {
    const int j = p * 512 + tid;
    const int row = j >> 3, G = j & 7;
    asrc[p] = A + (size_t)(m0 + row) * 1024 + (size_t)(G ^ (row & 7)) * 8;
    adst[p] = (j & ~63) * 8;
  }
#pragma unroll
  for (int p = 0; p < 2; ++p) {
    const int q = p * 512 + tid;
    const int row = q >> 3, G = q & 7;
    bsrc[p] = Bt + (size_t)(n0 + row) * 1024 + (size_t)(G ^ (row & 7)) * 8;
    bdst[p] = (q & ~63) * 8;
  }

  unsigned aoff[4][2], boff[4][2];
#pragma unroll
  for (int i = 0; i < 4; ++i) {
    const int ra = wr * 64 + i * 16 + l15;
    const int rb = wc * 64 + i * 16 + l15;
#pragma unroll
    for (int kh = 0; kh < 2; ++kh) {
      aoff[i][kh] = ra * 128 + (((kh * 4 + g) ^ (ra & 7)) * 16);
      boff[i][kh] = rb * 128 + (((kh * 4 + g) ^ (rb & 7)) * 16);
    }
  }

  auto STAGE = [&](int buf, int k0) {
#pragma unroll
    for (int p = 0; p < 4; ++p) GLOAD16(asrc[p] + k0, &As[buf][adst[p]]);
#pragma unroll
    for (int p = 0; p < 2; ++p) GLOAD16(bsrc[p] + k0, &Bs[buf][bdst[p]]);
  };

  STAGE(0, 0);
  STAGE(1, 64);
#pragma unroll 1
  for (int t = 0; t < 16; ++t) {
    if (t <= 14)
      asm volatile("s_waitcnt vmcnt(6)" ::: "memory");
    else
      asm volatile("s_waitcnt vmcnt(0)" ::: "memory");
    __builtin_amdgcn_s_barrier();
    const char* ab = (const char*)As + (t % 3) * 32768;
    const char* bb = (const char*)Bs + (t % 3) * 16384;
    const int nb = (t + 2) % 3;
    const int k2 = (t + 2) * 64;
    const bool more = (t + 2 < 16);
    // ---- phase 0 (kh=0): ds_read | A-stage slice | MFMA ----
    {
      bf16x8 af[4], bfr[4];
#pragma unroll
      for (int i = 0; i < 4; ++i) af[i] = *(const bf16x8*)(ab + aoff[i][0]);
#pragma unroll
      for (int j = 0; j < 4; ++j) bfr[j] = *(const bf16x8*)(bb + boff[j][0]);
      if (more) {
#pragma unroll
        for (int p = 0; p < 4; ++p) GLOAD16(asrc[p] + k2, &As[nb][adst[p]]);
      }
      __builtin_amdgcn_s_setprio(1);
#pragma unroll
      for (int i = 0; i < 4; ++i)
#pragma unroll
        for (int j = 0; j < 4; ++j) acc[i][j] = MFMA16(af[i], bfr[j], acc[i][j]);
      __builtin_amdgcn_s_setprio(0);
    }
    __builtin_amdgcn_s_barrier();
    // ---- phase 1 (kh=1): ds_read | B-stage slice | MFMA ----
    {
      bf16x8 af[4], bfr[4];
#pragma unroll
      for (int i = 0; i < 4; ++i) af[i] = *(const bf16x8*)(ab + aoff[i][1]);
#pragma unroll
      for (int j = 0; j < 4; ++j) bfr[j] = *(const bf16x8*)(bb + boff[j][1]);
      if (more) {
#pragma unroll
        for (int p = 0; p < 2; ++p) GLOAD16(bsrc[p] + k2, &Bs[nb][bdst[p]]);
      }
      __builtin_amdgcn_s_setprio(1);
#pragma unroll
      for (int i = 0; i < 4; ++i)
#pragma unroll
        for (int j = 0; j < 4; ++j) acc[i][j] = MFMA16(af[i], bfr[j], acc[i][j]);
      __builtin_amdgcn_s_setprio(0);
    }
    __builtin_amdgcn_s_barrier();
  }

  // C/D layout: col = lane&15, row = (lane>>4)*4 + reg.
#pragma unroll
  for (int i = 0; i < 4; ++i) {
#pragma unroll
    for (int j = 0; j < 4; ++j) {
      const int n = n0 + wc * 64 + j * 16 + l15;
      const float bv = bias[n];
      float vv[4];
#pragma unroll
      for (int r = 0; r < 4; ++r) vv[r] = acc[i][j][r] + bv;
      const int mb = m0 + wr * 64 + i * 16 + g * 4;
      if (EPI == 0) {
        const int three = n >> 10, h = (n >> 6) & 15, hd = n & 63;
        const int b = mb >> 11, s = mb & 2047;
        if (three == 2) {
          ushort4 pk;
          pk.x = f2bf(vv[0]); pk.y = f2bf(vv[1]);
          pk.z = f2bf(vv[2]); pk.w = f2bf(vv[3]);
          const int half = (s >> 5) & 1, hi16 = (s >> 4) & 1, gg = (s >> 2) & 3;
          const int col = (s & ~63) + (half * 4 + gg) * 8 + hi16 * 4;
          *(ushort4*)&o2[(((size_t)(b * 16 + h)) * 64 + hd) * 2048 + col] = pk;
        } else {
          const size_t idx0 = (((size_t)(b * 16 + h)) * 2048 + s) * 64 + hd;
#pragma unroll
          for (int r = 0; r < 4; ++r) {
            if (three == 0)
              o0[idx0 + (size_t)r * 64] = f2bf(vv[r] * 0.1803368801f);  // 0.125*log2e
            else
              o1[idx0 + (size_t)r * 64] = f2bf(vv[r]);
          }
        }
      } else {
#pragma unroll
        for (int r = 0; r < 4; ++r) of[(size_t)(mb + r) * 1024 + n] = vv[r];
      }
    }
  }
}

// Flash attention v14: v12 core + 3-buffer counted-vmcnt pipeline (the gemm8p
// recipe): raw s_barrier + s_waitcnt vmcnt(2) keeps the next tile's 2 stage
// loads in flight across barriers instead of draining to 0 each tile.
__global__ __launch_bounds__(512, 4) void attn_fwd(
    const unsigned short* __restrict__ Q, const unsigned short* __restrict__ Kq,
    const unsigned short* __restrict__ Vt, unsigned short* __restrict__ Ao) {
  __shared__ __align__(16) unsigned short Ks[3][4096];
  __shared__ __align__(16) unsigned short Vs[3][4096];
  const int blk = blockIdx.x;
  const int xcd = blk & 7, idx = blk >> 3;
  const int bh = xcd + 8 * (idx >> 3);
  const int qt = idx & 7;
  const int tid = threadIdx.x;
  const int lane = tid & 63;
  const int w = tid >> 6;
  const int g = lane >> 4, l15 = lane & 15;
  const int q0 = qt * 256 + w * 32;
  const unsigned short* Qp = Q + (size_t)bh * 2048 * 64;
  const unsigned short* Kp = Kq + (size_t)bh * 2048 * 64;
  const unsigned short* Vp = Vt + (size_t)bh * 64 * 2048;

  bf16x8 qf[2][2];
#pragma unroll
  for (int qg = 0; qg < 2; ++qg)
#pragma unroll
    for (int dh = 0; dh < 2; ++dh)
      qf[qg][dh] =
          *(const bf16x8*)&Qp[(size_t)(q0 + qg * 16 + l15) * 64 + dh * 32 + g * 8];

  const floatx4 minit = {-24.f, -24.f, -24.f, -24.f};
  const ushort8 onesu = {0x3F80, 0x3F80, 0x3F80, 0x3F80,
                         0x3F80, 0x3F80, 0x3F80, 0x3F80};
  const bf16x8 onesf = __builtin_bit_cast(bf16x8, onesu);
  floatx4 o[2][4], ol[2];
#pragma unroll
  for (int qg = 0; qg < 2; ++qg) {
#pragma unroll
    for (int tl = 0; tl < 4; ++tl) o[qg][tl] = {0.f, 0.f, 0.f, 0.f};
    ol[qg] = {0.f, 0.f, 0.f, 0.f};
  }

  const int x7 = l15 & 7;
  unsigned koffb[2];
#pragma unroll
  for (int dh = 0; dh < 2; ++dh)
    koffb[dh] = l15 * 128 + (((dh * 4 + g) ^ x7) * 16);
  const char* ksbase = (const char*)&Ks[0][0];
  const char* vsbase = (const char*)&Vs[0][0];

  const int j = tid;
  const int jsrc = (j & ~7) | ((j & 7) ^ ((j >> 3) & 7));
  const unsigned short* ksrc = Kp + jsrc * 8;
  const int vrow = j >> 3, sg = j & 7;
  const unsigned short* vsrc = Vp + (size_t)vrow * 2048 + (size_t)(sg ^ (vrow & 7)) * 8;
  const int dsto = (tid & ~63) * 8;

#define STAGE(BUF, kv0)                                                       \
  do {                                                                        \
    GLOAD16(ksrc + (size_t)(kv0) * 64, &Ks[BUF][dsto]);                       \
    GLOAD16(vsrc + (kv0), &Vs[BUF][dsto]);                                    \
  } while (0)

#define COMPUTE(BUF)                                                          \
  do {                                                                        \
    floatx4 s[2][4];                                                          \
    __builtin_amdgcn_s_setprio(1);                                            \
    _Pragma("unroll") for (int kvf = 0; kvf < 4; ++kvf) {                     \
      bf16x8 kf0 = *(const bf16x8*)(ksbase + (BUF)*8192 + kvf * 2048 +        \
                                    koffb[0]);                                \
      bf16x8 kf1 = *(const bf16x8*)(ksbase + (BUF)*8192 + kvf * 2048 +        \
                                    koffb[1]);                                \
      _Pragma("unroll") for (int qg = 0; qg < 2; ++qg) {                      \
        s[qg][kvf] = MFMA16(kf0, qf[qg][0], minit);                           \
        s[qg][kvf] = MFMA16(kf1, qf[qg][1], s[qg][kvf]);                      \
      }                                                                       \
    }                                                                         \
    __builtin_amdgcn_s_setprio(0);                                            \
    bf16x8 pf[2][2];                                                          \
    _Pragma("unroll") for (int qg = 0; qg < 2; ++qg) {                        \
      float p[4][4];                                                          \
      _Pragma("unroll") for (int kvf = 0; kvf < 4; ++kvf)                     \
          _Pragma("unroll") for (int r = 0; r < 4; ++r) p[kvf][r] =           \
          exp2f(s[qg][kvf][r]);                                               \
      uintx4 wa, wb;                                                          \
      wa[0] = pkbf(p[0][0], p[0][1]); wa[1] = pkbf(p[0][2], p[0][3]);         \
      wa[2] = pkbf(p[1][0], p[1][1]); wa[3] = pkbf(p[1][2], p[1][3]);         \
      wb[0] = pkbf(p[2][0], p[2][1]); wb[1] = pkbf(p[2][2], p[2][3]);         \
      wb[2] = pkbf(p[3][0], p[3][1]); wb[3] = pkbf(p[3][2], p[3][3]);         \
      pf[qg][0] = __builtin_bit_cast(bf16x8, wa);                             \
      pf[qg][1] = __builtin_bit_cast(bf16x8, wb);                             \
    }                                                                         \
    __builtin_amdgcn_s_setprio(1);                                            \
    ol[0] = MFMA16(pf[0][0], onesf, ol[0]);                                   \
    ol[0] = MFMA16(pf[0][1], onesf, ol[0]);                                   \
    ol[1] = MFMA16(pf[1][0], onesf, ol[1]);                                   \
    ol[1] = MFMA16(pf[1][1], onesf, ol[1]);                                   \
    _Pragma("unroll") for (int tl = 0; tl < 4; ++tl) {                        \
      _Pragma("unroll") for (int C = 0; C < 2; ++C) {                         \
        bf16x8 vf = *(const bf16x8*)(vsbase + (BUF)*8192 + tl * 2048 +        \
                                     koffb[C]);                               \
        o[0][tl] = MFMA16(pf[0][C], vf, o[0][tl]);                            \
        o[1][tl] = MFMA16(pf[1][C], vf, o[1][tl]);                            \
      }                                                                       \
    }                                                                         \
    __builtin_amdgcn_s_setprio(0);                                            \
  } while (0)

  STAGE(0, 0);
  STAGE(1, 64);
#pragma unroll 1
  for (int t = 0; t < 32; ++t) {
    if (t < 31)
      asm volatile("s_waitcnt vmcnt(2)" ::: "memory");
    else
      asm volatile("s_waitcnt vmcnt(0)" ::: "memory");
    __builtin_amdgcn_s_barrier();
    if (t + 2 < 32) STAGE((t + 2) % 3, (t + 2) * 64);
    COMPUTE(t % 3);
    __builtin_amdgcn_s_barrier();
  }
#undef STAGE
#undef COMPUTE

  const int b = bh >> 4, h = bh & 15;
#pragma unroll
  for (int qg = 0; qg < 2; ++qg) {
    float li[4];
#pragma unroll
    for (int r = 0; r < 4; ++r) li[r] = 1.0f / ol[qg][r];
#pragma unroll
    for (int tl = 0; tl < 4; ++tl)
#pragma unroll
      for (int r = 0; r < 4; ++r)
        Ao[((size_t)(b * 2048 + q0 + qg * 16 + g * 4 + r)) * 1024 + h * 64 +
           tl * 16 + l15] = f2bf(o[qg][tl][r] * li[r]);
  }
}

extern "C" void kernel_launch(void* const* d_in, const int* in_sizes, int n_in,
                              void* d_out, int out_size, void* d_ws, size_t ws_size,
                              hipStream_t stream) {
  float* outf = (float*)d_out;
  const size_t OUTN = (size_t)8192 * 1024;

  const float *x = nullptr, *Wqkv = nullptr, *bqkv = nullptr, *Wproj = nullptr,
              *bproj = nullptr;
  for (int i = 0; i < n_in; ++i) {
    switch (in_sizes[i]) {
      case 8388608: x = (const float*)d_in[i]; break;
      case 3145728: Wqkv = (const float*)d_in[i]; break;
      case 3072:    bqkv = (const float*)d_in[i]; break;
      case 1048576: Wproj = (const float*)d_in[i]; break;
      case 1024:    bproj = (const float*)d_in[i]; break;
      default: break;
    }
  }
  if (!x || !Wqkv || !bqkv || !Wproj || !bproj || n_in != 5) {
    fill_f32<<<2048, 256, 0, stream>>>(outf, 5000.0f, OUTN);
    return;
  }
  const size_t SZ = (size_t)4 * 16 * 2048 * 64 * 2;  // 16.78 MB
  const size_t WTP = (size_t)1024 * 1024 * 2;        // 2 MB
  if (ws_size < 3 * SZ + WTP) {
    fill_f32<<<2048, 256, 0, stream>>>(outf, 1000.0f + (float)(ws_size >> 20), OUTN);
    return;
  }

  char* ws = (char*)d_ws;
  unsigned short* xb = (unsigned short*)(ws);        // bf16 x; becomes Ao
  unsigned short* Kb = (unsigned short*)(ws + SZ);
  unsigned short* Vtb = (unsigned short*)(ws + 2 * SZ);
  unsigned short* Wtp = (unsigned short*)(ws + 3 * SZ);         // DEDICATED
  unsigned short* Qb = (unsigned short*)d_out;                  // lower half
  unsigned short* Wtq = (unsigned short*)((char*)d_out + SZ);   // upper half
  unsigned short* Ao = xb;                                      // x dead post-gemm0

  prep_fused<<<5120, 256, 0, stream>>>(x, xb, Wqkv, Wtq, Wproj, Wtp);
  gemm8p<24, 0><<<768, 512, 0, stream>>>(
      xb, Wtq, bqkv, Qb, Kb, Vtb, nullptr);
  attn_fwd<<<512, 512, 0, stream>>>(Qb, Kb, Vtb, Ao);
  gemm8p<8, 1><<<256, 512, 0, stream>>>(
      Ao, Wtp, bproj, nullptr, nullptr, nullptr, outf);
}

// Round 25
// 200.138 us; speedup vs baseline: 1.0203x; 1.0203x over previous
//
#include <hip/hip_runtime.h>

// B=4, S=2048, D=1024, H=16, HD=64. Inputs fp32, OUTPUT fp32.
// Intermediates bf16. ws: xb/Ao + Kb + Vtb + Wtp = 52.4MB.
// d_out double-duty: lower half = Q (bf16), upper half = Wtq (bf16) until proj.
typedef __bf16 bf16x8 __attribute__((ext_vector_type(8)));
typedef unsigned short ushort8 __attribute__((ext_vector_type(8)));
typedef float floatx4 __attribute__((ext_vector_type(4)));
typedef unsigned int uintx4 __attribute__((ext_vector_type(4)));

__device__ __forceinline__ unsigned short f2bf(float f) {
  unsigned int u = __builtin_bit_cast(unsigned int, f);
  u += 0x7fffu + ((u >> 16) & 1u);
  return (unsigned short)(u >> 16);
}
__device__ __forceinline__ unsigned int pkbf(float a, float b) {
  unsigned int r;
  asm("v_cvt_pk_bf16_f32 %0, %1, %2" : "=v"(r) : "v"(a), "v"(b));
  return r;
}
__device__ __forceinline__ floatx4 MFMA16(bf16x8 a, bf16x8 b, floatx4 c) {
  return __builtin_amdgcn_mfma_f32_16x16x32_bf16(a, b, c, 0, 0, 0);
}

#define GLOAD16(gsrc, ldst)                                                  \
  __builtin_amdgcn_global_load_lds(                                          \
      (const __attribute__((address_space(1))) void*)(gsrc),                 \
      (__attribute__((address_space(3))) void*)(ldst), 16, 0, 0)

__global__ __launch_bounds__(256) void fill_f32(
    float* __restrict__ out, float val, size_t n) {
  const size_t t = (size_t)blockIdx.x * 256 + threadIdx.x;
  for (size_t i = t; i < n; i += (size_t)gridDim.x * 256) out[i] = val;
}

// Fused prep: [0,4096) x fp32->bf16; [4096,4864) Wqkv transpose (48x16);
// [4864,5120) Wproj transpose (16x16). Wtp is a DEDICATED buffer (no alias).
__global__ __launch_bounds__(256) void prep_fused(
    const float* __restrict__ x, unsigned short* __restrict__ xb,
    const float* __restrict__ Wqkv, unsigned short* __restrict__ Wtq,
    const float* __restrict__ Wproj, unsigned short* __restrict__ Wtp) {
  const int blk = blockIdx.x;
  const int tid = threadIdx.x;
  if (blk < 4096) {  // cvt: 8 elems/thread
    const size_t t = (size_t)blk * 256 + tid;
    const float4 a = ((const float4*)x)[2 * t];
    const float4 b = ((const float4*)x)[2 * t + 1];
    uintx4 u;
    u[0] = pkbf(a.x, a.y); u[1] = pkbf(a.z, a.w);
    u[2] = pkbf(b.x, b.y); u[3] = pkbf(b.z, b.w);
    *(uintx4*)&xb[t * 8] = u;
    return;
  }
  const float* in;
  unsigned short* out;
  int C, bx, by;
  if (blk < 4864) {
    in = Wqkv; out = Wtq; C = 3072;
    const int b2 = blk - 4096;           // 48 x 16
    bx = b2 % 48; by = b2 / 48;
  } else {
    in = Wproj; out = Wtp; C = 1024;
    const int b2 = blk - 4864;           // 16 x 16
    bx = b2 % 16; by = b2 / 16;
  }
  __shared__ float T[64][65];
  const int r0 = by * 64, c0 = bx * 64;
#pragma unroll
  for (int e = 0; e < 4; ++e) {
    const int idx = e * 256 + tid;
    const int row = idx >> 4, cg = idx & 15;
    const float4 f = *(const float4*)&in[(size_t)(r0 + row) * C + c0 + cg * 4];
    T[row][cg * 4] = f.x; T[row][cg * 4 + 1] = f.y;
    T[row][cg * 4 + 2] = f.z; T[row][cg * 4 + 3] = f.w;
  }
  __syncthreads();
#pragma unroll
  for (int e = 0; e < 2; ++e) {
    const int idx = e * 256 + tid;
    const int cc = idx >> 3, rg = idx & 7;
    uintx4 u;
#pragma unroll
    for (int k = 0; k < 4; ++k)
      u[k] = pkbf(T[rg * 8 + 2 * k][cc], T[rg * 8 + 2 * k + 1][cc]);
    *(uintx4*)&out[(size_t)(c0 + cc) * 1024 + r0 + rg * 8] = u;
  }
}

// C[8192, NBX*128] = A[8192,1024](bf16) @ Bt[NBX*128,1024](bf16)^T + bias.
// BM=256, BN=128, BK=64, 8 waves. 3-deep LDS pipeline, counted vmcnt(6),
// PHASE-SPLIT body (T3+T4). XOR-swizzled LDS (both-sides).
template <int NBX, int EPI>
__global__ __launch_bounds__(512) void gemm8p(
    const unsigned short* __restrict__ A, const unsigned short* __restrict__ Bt,
    const float* __restrict__ bias, unsigned short* __restrict__ o0,
    unsigned short* __restrict__ o1, unsigned short* __restrict__ o2,
    float* __restrict__ of) {
  __shared__ __align__(16) unsigned short As[3][256 * 64];
  __shared__ __align__(16) unsigned short Bs[3][128 * 64];
  const int tid = threadIdx.x;
  const int lane = tid & 63;
  const int w = tid >> 6;
  const int g = lane >> 4, l15 = lane & 15;
  const int wr = w >> 1, wc = w & 1;
  constexpr int QX = 4 * NBX;
  const int orig = blockIdx.x;
  const int wgid = (orig & 7) * QX + (orig >> 3);
  const int m0 = (wgid / NBX) * 256, n0 = (wgid % NBX) * 128;

  floatx4 acc[4][4];
#pragma unroll
  for (int i = 0; i < 4; ++i)
#pragma unroll
    for (int j = 0; j < 4; ++j) acc[i][j] = {0.f, 0.f, 0.f, 0.f};

  const unsigned short* asrc[4];
  const unsigned short* bsrc[2];
  int adst[4], bdst[2];
#pragma unroll
  for (int p = 0; p < 4; ++p) {
    const int j = p * 512 + tid;
    const int row = j >> 3, G = j & 7;
    asrc[p] = A + (size_t)(m0 + row) * 1024 + (size_t)(G ^ (row & 7)) * 8;
    adst[p] = (j & ~63) * 8;
  }
#pragma unroll
  for (int p = 0; p < 2; ++p) {
    const int q = p * 512 + tid;
    const int row = q >> 3, G = q & 7;
    bsrc[p] = Bt + (size_t)(n0 + row) * 1024 + (size_t)(G ^ (row & 7)) * 8;
    bdst[p] = (q & ~63) * 8;
  }

  unsigned aoff[4][2], boff[4][2];
#pragma unroll
  for (int i = 0; i < 4; ++i) {
    const int ra = wr * 64 + i * 16 + l15;
    const int rb = wc * 64 + i * 16 + l15;
#pragma unroll
    for (int kh = 0; kh < 2; ++kh) {
      aoff[i][kh] = ra * 128 + (((kh * 4 + g) ^ (ra & 7)) * 16);
      boff[i][kh] = rb * 128 + (((kh * 4 + g) ^ (rb & 7)) * 16);
    }
  }

  auto STAGE = [&](int buf, int k0) {
#pragma unroll
    for (int p = 0; p < 4; ++p) GLOAD16(asrc[p] + k0, &As[buf][adst[p]]);
#pragma unroll
    for (int p = 0; p < 2; ++p) GLOAD16(bsrc[p] + k0, &Bs[buf][bdst[p]]);
  };

  STAGE(0, 0);
  STAGE(1, 64);
#pragma unroll 1
  for (int t = 0; t < 16; ++t) {
    if (t <= 14)
      asm volatile("s_waitcnt vmcnt(6)" ::: "memory");
    else
      asm volatile("s_waitcnt vmcnt(0)" ::: "memory");
    __builtin_amdgcn_s_barrier();
    const char* ab = (const char*)As + (t % 3) * 32768;
    const char* bb = (const char*)Bs + (t % 3) * 16384;
    const int nb = (t + 2) % 3;
    const int k2 = (t + 2) * 64;
    const bool more = (t + 2 < 16);
    // ---- phase 0 (kh=0): ds_read | A-stage slice | MFMA ----
    {
      bf16x8 af[4], bfr[4];
#pragma unroll
      for (int i = 0; i < 4; ++i) af[i] = *(const bf16x8*)(ab + aoff[i][0]);
#pragma unroll
      for (int j = 0; j < 4; ++j) bfr[j] = *(const bf16x8*)(bb + boff[j][0]);
      if (more) {
#pragma unroll
        for (int p = 0; p < 4; ++p) GLOAD16(asrc[p] + k2, &As[nb][adst[p]]);
      }
      __builtin_amdgcn_s_setprio(1);
#pragma unroll
      for (int i = 0; i < 4; ++i)
#pragma unroll
        for (int j = 0; j < 4; ++j) acc[i][j] = MFMA16(af[i], bfr[j], acc[i][j]);
      __builtin_amdgcn_s_setprio(0);
    }
    __builtin_amdgcn_s_barrier();
    // ---- phase 1 (kh=1): ds_read | B-stage slice | MFMA ----
    {
      bf16x8 af[4], bfr[4];
#pragma unroll
      for (int i = 0; i < 4; ++i) af[i] = *(const bf16x8*)(ab + aoff[i][1]);
#pragma unroll
      for (int j = 0; j < 4; ++j) bfr[j] = *(const bf16x8*)(bb + boff[j][1]);
      if (more) {
#pragma unroll
        for (int p = 0; p < 2; ++p) GLOAD16(bsrc[p] + k2, &Bs[nb][bdst[p]]);
      }
      __builtin_amdgcn_s_setprio(1);
#pragma unroll
      for (int i = 0; i < 4; ++i)
#pragma unroll
        for (int j = 0; j < 4; ++j) acc[i][j] = MFMA16(af[i], bfr[j], acc[i][j]);
      __builtin_amdgcn_s_setprio(0);
    }
    __builtin_amdgcn_s_barrier();
  }

  // C/D layout: col = lane&15, row = (lane>>4)*4 + reg.
#pragma unroll
  for (int i = 0; i < 4; ++i) {
#pragma unroll
    for (int j = 0; j < 4; ++j) {
      const int n = n0 + wc * 64 + j * 16 + l15;
      const float bv = bias[n];
      float vv[4];
#pragma unroll
      for (int r = 0; r < 4; ++r) vv[r] = acc[i][j][r] + bv;
      const int mb = m0 + wr * 64 + i * 16 + g * 4;
      if (EPI == 0) {
        const int three = n >> 10, h = (n >> 6) & 15, hd = n & 63;
        const int b = mb >> 11, s = mb & 2047;
        if (three == 2) {
          ushort4 pk;
          pk.x = f2bf(vv[0]); pk.y = f2bf(vv[1]);
          pk.z = f2bf(vv[2]); pk.w = f2bf(vv[3]);
          const int half = (s >> 5) & 1, hi16 = (s >> 4) & 1, gg = (s >> 2) & 3;
          const int col = (s & ~63) + (half * 4 + gg) * 8 + hi16 * 4;
          *(ushort4*)&o2[(((size_t)(b * 16 + h)) * 64 + hd) * 2048 + col] = pk;
        } else {
          const size_t idx0 = (((size_t)(b * 16 + h)) * 2048 + s) * 64 + hd;
#pragma unroll
          for (int r = 0; r < 4; ++r) {
            if (three == 0)
              o0[idx0 + (size_t)r * 64] = f2bf(vv[r] * 0.1803368801f);  // 0.125*log2e
            else
              o1[idx0 + (size_t)r * 64] = f2bf(vv[r]);
          }
        }
      } else {
#pragma unroll
        for (int r = 0; r < 4; ++r) of[(size_t)(mb + r) * 1024 + n] = vv[r];
      }
    }
  }
}

// Flash attention v12 (round-23 measured-best, reverted from v14): 512 thr =
// 8 waves, 32 q-rows/wave (qg=2), KVBLK=64, conflict-free K/V, XCD colocation,
// fixed-shift softmax (C-init -24), ones-column denominator on matrix pipe.
__global__ __launch_bounds__(512, 4) void attn_fwd(
    const unsigned short* __restrict__ Q, const unsigned short* __restrict__ Kq,
    const unsigned short* __restrict__ Vt, unsigned short* __restrict__ Ao) {
  __shared__ __align__(16) unsigned short Ks[2][4096];
  __shared__ __align__(16) unsigned short Vs[2][4096];
  const int blk = blockIdx.x;
  const int xcd = blk & 7, idx = blk >> 3;
  const int bh = xcd + 8 * (idx >> 3);
  const int qt = idx & 7;
  const int tid = threadIdx.x;
  const int lane = tid & 63;
  const int w = tid >> 6;
  const int g = lane >> 4, l15 = lane & 15;
  const int q0 = qt * 256 + w * 32;
  const unsigned short* Qp = Q + (size_t)bh * 2048 * 64;
  const unsigned short* Kp = Kq + (size_t)bh * 2048 * 64;
  const unsigned short* Vp = Vt + (size_t)bh * 64 * 2048;

  bf16x8 qf[2][2];
#pragma unroll
  for (int qg = 0; qg < 2; ++qg)
#pragma unroll
    for (int dh = 0; dh < 2; ++dh)
      qf[qg][dh] =
          *(const bf16x8*)&Qp[(size_t)(q0 + qg * 16 + l15) * 64 + dh * 32 + g * 8];

  const floatx4 minit = {-24.f, -24.f, -24.f, -24.f};
  const ushort8 onesu = {0x3F80, 0x3F80, 0x3F80, 0x3F80,
                         0x3F80, 0x3F80, 0x3F80, 0x3F80};
  const bf16x8 onesf = __builtin_bit_cast(bf16x8, onesu);
  floatx4 o[2][4], ol[2];
#pragma unroll
  for (int qg = 0; qg < 2; ++qg) {
#pragma unroll
    for (int tl = 0; tl < 4; ++tl) o[qg][tl] = {0.f, 0.f, 0.f, 0.f};
    ol[qg] = {0.f, 0.f, 0.f, 0.f};
  }

  const int x7 = l15 & 7;
  unsigned koffb[2];
#pragma unroll
  for (int dh = 0; dh < 2; ++dh)
    koffb[dh] = l15 * 128 + (((dh * 4 + g) ^ x7) * 16);
  const char* ksbase = (const char*)&Ks[0][0];
  const char* vsbase = (const char*)&Vs[0][0];

  const int j = tid;
  const int jsrc = (j & ~7) | ((j & 7) ^ ((j >> 3) & 7));
  const unsigned short* ksrc = Kp + jsrc * 8;
  const int vrow = j >> 3, sg = j & 7;
  const unsigned short* vsrc = Vp + (size_t)vrow * 2048 + (size_t)(sg ^ (vrow & 7)) * 8;
  const int dsto = (tid & ~63) * 8;

#define STAGE(BUF, kv0)                                                       \
  do {                                                                        \
    GLOAD16(ksrc + (size_t)(kv0) * 64, &Ks[BUF][dsto]);                       \
    GLOAD16(vsrc + (kv0), &Vs[BUF][dsto]);                                    \
  } while (0)

#define COMPUTE(BUF)                                                          \
  do {                                                                        \
    floatx4 s[2][4];                                                          \
    __builtin_amdgcn_s_setprio(1);                                            \
    _Pragma("unroll") for (int kvf = 0; kvf < 4; ++kvf) {                     \
      bf16x8 kf0 = *(const bf16x8*)(ksbase + (BUF)*8192 + kvf * 2048 +        \
                                    koffb[0]);                                \
      bf16x8 kf1 = *(const bf16x8*)(ksbase + (BUF)*8192 + kvf * 2048 +        \
                                    koffb[1]);                                \
      _Pragma("unroll") for (int qg = 0; qg < 2; ++qg) {                      \
        s[qg][kvf] = MFMA16(kf0, qf[qg][0], minit);                           \
        s[qg][kvf] = MFMA16(kf1, qf[qg][1], s[qg][kvf]);                      \
      }                                                                       \
    }                                                                         \
    __builtin_amdgcn_s_setprio(0);                                            \
    bf16x8 pf[2][2];                                                          \
    _Pragma("unroll") for (int qg = 0; qg < 2; ++qg) {                        \
      float p[4][4];                                                          \
      _Pragma("unroll") for (int kvf = 0; kvf < 4; ++kvf)                     \
          _Pragma("unroll") for (int r = 0; r < 4; ++r) p[kvf][r] =           \
          exp2f(s[qg][kvf][r]);                                               \
      uintx4 wa, wb;                                                          \
      wa[0] = pkbf(p[0][0], p[0][1]); wa[1] = pkbf(p[0][2], p[0][3]);         \
      wa[2] = pkbf(p[1][0], p[1][1]); wa[3] = pkbf(p[1][2], p[1][3]);         \
      wb[0] = pkbf(p[2][0], p[2][1]); wb[1] = pkbf(p[2][2], p[2][3]);         \
      wb[2] = pkbf(p[3][0], p[3][1]); wb[3] = pkbf(p[3][2], p[3][3]);         \
      pf[qg][0] = __builtin_bit_cast(bf16x8, wa);                             \
      pf[qg][1] = __builtin_bit_cast(bf16x8, wb);                             \
    }                                                                         \
    __builtin_amdgcn_s_setprio(1);                                            \
    ol[0] = MFMA16(pf[0][0], onesf, ol[0]);                                   \
    ol[0] = MFMA16(pf[0][1], onesf, ol[0]);                                   \
    ol[1] = MFMA16(pf[1][0], onesf, ol[1]);                                   \
    ol[1] = MFMA16(pf[1][1], onesf, ol[1]);                                   \
    _Pragma("unroll") for (int tl = 0; tl < 4; ++tl) {                        \
      _Pragma("unroll") for (int C = 0; C < 2; ++C) {                         \
        bf16x8 vf = *(const bf16x8*)(vsbase + (BUF)*8192 + tl * 2048 +        \
                                     koffb[C]);                               \
        o[0][tl] = MFMA16(pf[0][C], vf, o[0][tl]);                            \
        o[1][tl] = MFMA16(pf[1][C], vf, o[1][tl]);                            \
      }                                                                       \
    }                                                                         \
    __builtin_amdgcn_s_setprio(0);                                            \
  } while (0)

  STAGE(0, 0);
  __syncthreads();
#pragma unroll 1
  for (int t0 = 0; t0 < 32; t0 += 2) {
    STAGE(1, (t0 + 1) * 64);
    COMPUTE(0);
    __syncthreads();
    if (t0 + 2 < 32) STAGE(0, (t0 + 2) * 64);
    COMPUTE(1);
    __syncthreads();
  }
#undef STAGE
#undef COMPUTE

  const int b = bh >> 4, h = bh & 15;
#pragma unroll
  for (int qg = 0; qg < 2; ++qg) {
    float li[4];
#pragma unroll
    for (int r = 0; r < 4; ++r) li[r] = 1.0f / ol[qg][r];
#pragma unroll
    for (int tl = 0; tl < 4; ++tl)
#pragma unroll
      for (int r = 0; r < 4; ++r)
        Ao[((size_t)(b * 2048 + q0 + qg * 16 + g * 4 + r)) * 1024 + h * 64 +
           tl * 16 + l15] = f2bf(o[qg][tl][r] * li[r]);
  }
}

extern "C" void kernel_launch(void* const* d_in, const int* in_sizes, int n_in,
                              void* d_out, int out_size, void* d_ws, size_t ws_size,
                              hipStream_t stream) {
  float* outf = (float*)d_out;
  const size_t OUTN = (size_t)8192 * 1024;

  const float *x = nullptr, *Wqkv = nullptr, *bqkv = nullptr, *Wproj = nullptr,
              *bproj = nullptr;
  for (int i = 0; i < n_in; ++i) {
    switch (in_sizes[i]) {
      case 8388608: x = (const float*)d_in[i]; break;
      case 3145728: Wqkv = (const float*)d_in[i]; break;
      case 3072:    bqkv = (const float*)d_in[i]; break;
      case 1048576: Wproj = (const float*)d_in[i]; break;
      case 1024:    bproj = (const float*)d_in[i]; break;
      default: break;
    }
  }
  if (!x || !Wqkv || !bqkv || !Wproj || !bproj || n_in != 5) {
    fill_f32<<<2048, 256, 0, stream>>>(outf, 5000.0f, OUTN);
    return;
  }
  const size_t SZ = (size_t)4 * 16 * 2048 * 64 * 2;  // 16.78 MB
  const size_t WTP = (size_t)1024 * 1024 * 2;        // 2 MB
  if (ws_size < 3 * SZ + WTP) {
    fill_f32<<<2048, 256, 0, stream>>>(outf, 1000.0f + (float)(ws_size >> 20), OUTN);
    return;
  }

  char* ws = (char*)d_ws;
  unsigned short* xb = (unsigned short*)(ws);        // bf16 x; becomes Ao
  unsigned short* Kb = (unsigned short*)(ws + SZ);
  unsigned short* Vtb = (unsigned short*)(ws + 2 * SZ);
  unsigned short* Wtp = (unsigned short*)(ws + 3 * SZ);         // DEDICATED
  unsigned short* Qb = (unsigned short*)d_out;                  // lower half
  unsigned short* Wtq = (unsigned short*)((char*)d_out + SZ);   // upper half
  unsigned short* Ao = xb;                                      // x dead post-gemm0

  prep_fused<<<5120, 256, 0, stream>>>(x, xb, Wqkv, Wtq, Wproj, Wtp);
  gemm8p<24, 0><<<768, 512, 0, stream>>>(
      xb, Wtq, bqkv, Qb, Kb, Vtb, nullptr);
  attn_fwd<<<512, 512, 0, stream>>>(Qb, Kb, Vtb, Ao);
  gemm8p<8, 1><<<256, 512, 0, stream>>>(
      Ao, Wtp, bproj, nullptr, nullptr, nullptr, outf);
}